// Round 6
// baseline (1168.893 us; speedup 1.0000x reference)
//
#include <hip/hip_runtime.h>
#include <hip/hip_fp16.h>
#include <math.h>

#define BB 2
#define HH 96
#define WW 160
#define HW (HH*WW)

typedef short bf16x8 __attribute__((ext_vector_type(8)));
typedef float f32x4  __attribute__((ext_vector_type(4)));

__device__ inline unsigned short f2bf(float v) {
    unsigned u = __float_as_uint(v);
    unsigned r = (u + 0x7FFF + ((u >> 16) & 1)) >> 16;   // RNE
    return (unsigned short)r;
}
__device__ inline float bf2f(unsigned short s) {
    return __uint_as_float(((unsigned)s) << 16);
}

// Split fp32 conv weights into hi/lo bf16, layout [tap][ocP][icP] (zero-padded).
__global__ __launch_bounds__(256) void wsplit_k(
    const float* __restrict__ src, int Cout, int Cin, int OCP, int ICP,
    unsigned short* __restrict__ dh, unsigned short* __restrict__ dl)
{
    int idx = blockIdx.x * 256 + threadIdx.x;
    if (idx >= 9 * OCP * ICP) return;
    int ic  = idx % ICP;
    int q   = idx / ICP;
    int oc  = q % OCP;
    int tap = q / OCP;
    float v = (oc < Cout && ic < Cin) ? src[((size_t)oc * Cin + ic) * 9 + tap] : 0.f;
    unsigned short hs = f2bf(v);
    dh[idx] = hs;
    dl[idx] = f2bf(v - bf2f(hs));
}

// ===========================================================================
// Split-bf16 MFMA 3x3 conv.  BM=128 oc, BN = 4 rows x 32 cols = 128 px, BK=32.
// (unchanged from R5 — see R5 notes)
// ===========================================================================
#define LOADA(DH, DL, TAP) {                                                          \
    const size_t wb_ = ((size_t)((TAP) * OCP + mblk * 128 + wm * 64 + lc)) * ICP      \
                       + kbase + lr * 8;                                              \
    _Pragma("unroll")                                                                 \
    for (int mf_ = 0; mf_ < 4; ++mf_) {                                               \
        DH[mf_] = *(const bf16x8*)(Wh + wb_ + (size_t)mf_ * 16 * ICP);                \
        DL[mf_] = *(const bf16x8*)(Wl + wb_ + (size_t)mf_ * 16 * ICP);                \
    } }

template<int IN_MODE, int EPI, int NCHUNK, int ICP, int OCP>
__global__ __launch_bounds__(256, 2) void conv_mfma(
    const float* __restrict__ ef, const float* __restrict__ f1, const float* __restrict__ f2,
    const unsigned short* __restrict__ inH, const unsigned short* __restrict__ inL,
    const unsigned short* __restrict__ Wh, const unsigned short* __restrict__ Wl,
    const float* __restrict__ bias,
    unsigned short* __restrict__ outH, unsigned short* __restrict__ outL,
    __half* __restrict__ h3)
{
    __shared__ char lds_c[30720];            // [pl2][row6][col40][ic32] bf16, swizzled

    const int t  = threadIdx.x;
    const int l  = t & 63;
    const int lr = l >> 4;                   // 0..3 (k-quarter)
    const int lc = l & 15;                   // 0..15
    const int wv = __builtin_amdgcn_readfirstlane(t >> 6);
    const int wm = wv >> 1, wn = wv & 1;

    const int colseg  = blockIdx.x;          // 0..4  (32 cols)
    const int rowquad = blockIdx.y;          // 0..23 (4 rows)
    const int MB      = OCP / 128;
    const int b       = blockIdx.z / MB;
    const int mblk    = blockIdx.z % MB;

    f32x4 acc[4][4];
#pragma unroll
    for (int m = 0; m < 4; ++m)
#pragma unroll
        for (int n = 0; n < 4; ++n)
#pragma unroll
            for (int j = 0; j < 4; ++j) acc[m][n][j] = 0.f;

    const int pixbase = b * HW;

    for (int chunk = 0; chunk < NCHUNK; ++chunk) {
        const int kbase = chunk * 32;

        if (IN_MODE == 0) {
            for (int s = t; s < 1632; s += 256) {
                int icg = s & 3;
                int q   = s >> 2;
                int col = q % 34;
                int r   = q / 34;            // 0..11 = pl*6 + row
                int row = r % 6;
                int pl  = r / 6;
                int gh = rowquad * 4 + row - 1;
                int gw = colseg * 32 + col - 1;
                bf16x8 v;
#pragma unroll
                for (int i = 0; i < 8; ++i) v[i] = 0;
                if ((unsigned)gh < (unsigned)HH && (unsigned)gw < (unsigned)WW) {
                    const unsigned short* src = pl ? inL : inH;
                    v = *(const bf16x8*)(src + (size_t)(pixbase + gh * WW + gw) * ICP + kbase + icg * 8);
                }
                int ebyte = ((row * 40 + col) << 6) + (icg << 4);
                int byte  = (ebyte ^ ((col & 7) << 4)) + pl * 15360;
                *(bf16x8*)(lds_c + byte) = v;
            }
        } else {
            for (int s = t; s < 6528; s += 256) {
                int ic  = s / 204;
                int rem = s - ic * 204;
                int col = rem % 34;
                int row = rem / 34;
                int c   = kbase + ic;
                int gh = rowquad * 4 + row - 1;
                int gw = colseg * 32 + col - 1;
                float v = 0.f;
                if ((unsigned)gh < (unsigned)HH && (unsigned)gw < (unsigned)WW) {
                    int pix = gh * WW + gw;
                    if (c < 384)      v = ef[((size_t)(b * 384 + c)) * HW + pix];
                    else if (c < 386) v = f1[((size_t)(b * 2 + c - 384)) * HW + pix];
                    else if (c < 388) v = f2[((size_t)(b * 2 + c - 386)) * HW + pix];
                }
                unsigned short hs = f2bf(v);
                unsigned short ls = f2bf(v - bf2f(hs));
                int ebyte = (row * 40 + col) * 64 + ic * 2;
                int sw    = (col & 7) << 4;
                *(unsigned short*)(lds_c + (ebyte ^ sw))          = hs;
                *(unsigned short*)(lds_c + (ebyte ^ sw) + 15360)  = ls;
            }
        }
        __syncthreads();

        bf16x8 Ah0[4], Al0[4], Ah1[4], Al1[4];
        LOADA(Ah0, Al0, 0);
#pragma unroll
        for (int tap = 0; tap < 9; ++tap) {
            const int ky = tap / 3, kx = tap % 3;
            bf16x8 Bh[4], Bl[4];
#pragma unroll
            for (int nf = 0; nf < 4; ++nf) {
                int rsub = nf >> 1, chf = nf & 1;
                int row  = ky + wn * 2 + rsub;
                int col  = kx + chf * 16 + lc;
                int byte = (((row * 40 + col) << 6) + (lr << 4)) ^ ((col & 7) << 4);
                Bh[nf] = *(const bf16x8*)(lds_c + byte);
                Bl[nf] = *(const bf16x8*)(lds_c + byte + 15360);
            }
            if (tap < 8) { LOADA(Ah1, Al1, tap + 1); }
            __builtin_amdgcn_s_setprio(1);
#pragma unroll
            for (int mf = 0; mf < 4; ++mf) {
#pragma unroll
                for (int nf = 0; nf < 4; ++nf) {
                    acc[mf][nf] = __builtin_amdgcn_mfma_f32_16x16x32_bf16(Al0[mf], Bh[nf], acc[mf][nf], 0, 0, 0);
                    acc[mf][nf] = __builtin_amdgcn_mfma_f32_16x16x32_bf16(Ah0[mf], Bl[nf], acc[mf][nf], 0, 0, 0);
                    acc[mf][nf] = __builtin_amdgcn_mfma_f32_16x16x32_bf16(Ah0[mf], Bh[nf], acc[mf][nf], 0, 0, 0);
                }
            }
            __builtin_amdgcn_s_setprio(0);
            if (tap < 8) {
#pragma unroll
                for (int mf = 0; mf < 4; ++mf) {
                    Ah0[mf] = Ah1[mf];
                    Al0[mf] = Al1[mf];
                }
            }
        }
        __syncthreads();
    }

#pragma unroll
    for (int mf = 0; mf < 4; ++mf) {
        const int ocb = wm * 64 + mf * 16 + lr * 4;
#pragma unroll
        for (int nf = 0; nf < 4; ++nf) {
            const int rsub = nf >> 1, chf = nf & 1;
            const int h = rowquad * 4 + wn * 2 + rsub;
            const int w = colseg * 32 + chf * 16 + lc;
#pragma unroll
            for (int j = 0; j < 4; ++j) {
                float v = acc[mf][nf][j];
                if (EPI == 1) {
                    int oc = ocb + j;
                    v += bias[oc];
                    v = (v >= 0.f) ? v : 0.1f * v;
                    size_t idx = (size_t)(pixbase + h * WW + w) * 128 + oc;
                    unsigned short hs = f2bf(v);
                    outH[idx] = hs;
                    outL[idx] = f2bf(v - bf2f(hs));
                } else {
                    int oc = mblk * 128 + ocb + j;
                    if (oc < 432) {
                        v += bias[oc];
                        size_t idx = ((size_t)(b * 432 + oc)) * HW + h * WW + w;
                        if (oc < 288) {
                            float e  = __expf(2.f * v);
                            float th = 1.f - 2.f / (e + 1.f);
                            float off = 10.f * th;
                            const float* fl = (oc < 144) ? f1 : f2;
                            off += fl[((size_t)(b * 2 + (1 - (oc & 1)))) * HW + h * WW + w];
                            h3[idx] = __float2half(off);
                        } else {
                            h3[idx] = __float2half(1.f / (1.f + __expf(-v)));
                        }
                    }
                }
            }
        }
    }
}

// Weight transpose for deform: wT[(pair*8 + c)*128 + oc] = w[oc][g*8+c][k].
__global__ __launch_bounds__(256) void wtrans_k(const float* __restrict__ w, float* __restrict__ wT)
{
    int tid = blockIdx.x * 256 + threadIdx.x;
    if (tid < 128 * 128 * 9) {
        int oc   = tid & 127;
        int pc   = tid >> 7;
        int c    = pc & 7;
        int pair = pc >> 3;
        int g    = pair / 9, k = pair - g * 9;
        wT[tid] = w[((size_t)(oc * 128) + g * 8 + c) * 9 + k];
    }
}

// x NCHW -> NHWC fp32 (xt[b][pix][128]) via LDS tile, coalesced both sides.
__global__ __launch_bounds__(256) void xt_k(const float* __restrict__ x, float* __restrict__ xt)
{
    __shared__ float tl[128][65];
    const int b   = blockIdx.y;
    const int px0 = blockIdx.x * 64;
    const int t   = threadIdx.x;
    const int pxr = t & 63;
#pragma unroll
    for (int i = 0; i < 32; ++i) {
        int c = (t >> 6) * 32 + i;
        tl[c][pxr] = x[((size_t)(b * 128) + c) * HW + px0 + pxr];
    }
    __syncthreads();
    const int px = t >> 2, c0 = (t & 3) * 32;
    float* dst = xt + ((size_t)(b * HW) + px0 + px) * 128 + c0;
#pragma unroll
    for (int i = 0; i < 8; ++i) {
        f32x4 v;
        v[0] = tl[c0 + i * 4 + 0][px];
        v[1] = tl[c0 + i * 4 + 1][px];
        v[2] = tl[c0 + i * 4 + 2][px];
        v[3] = tl[c0 + i * 4 + 3][px];
        *(f32x4*)(dst + i * 4) = v;
    }
}

__global__ __launch_bounds__(256) void init_out_k(const float* __restrict__ bias, float* __restrict__ out)
{
    int idx = blockIdx.x * 256 + threadIdx.x;
    if (idx < BB * 128 * HW) {
        int oc = (idx / HW) & 127;
        out[idx] = bias[oc];
    }
}

// ===========================================================================
// Deformable conv v3: thread = sample-site, NHWC gather, 2-deep pipeline.
// Block 256 thr / 4 waves, 8x8 px tile, 4 of 16 groups (gs).  Chunk = 4 pairs.
// Iter body: {h3 loads (ch+2) | corner loads (ch+1) | 1024 FMA (ch) |
//             bilinear+LDS write (ch+1) | barrier}.  1 barrier/chunk.
// ===========================================================================
__device__ __forceinline__ void bilinear8(
    const f32x4& a0, const f32x4& b0, const f32x4& a1, const f32x4& b1,
    const f32x4& a2, const f32x4& b2, const f32x4& a3, const f32x4& b3,
    float w00, float w01, float w10, float w11, float* val)
{
#pragma unroll
    for (int i = 0; i < 4; ++i) {
        val[i]     = w00 * a0[i] + w01 * a1[i] + w10 * a2[i] + w11 * a3[i];
        val[i + 4] = w00 * b0[i] + w01 * b1[i] + w10 * b2[i] + w11 * b3[i];
    }
}

__global__ __launch_bounds__(256, 4) void deform3_k(
    const float* __restrict__ xt, const __half* __restrict__ h3,
    const float* __restrict__ wT, float* __restrict__ out)
{
    __shared__ float s_val[2][4][8][64];

    const int t  = threadIdx.x;
    const int p  = t & 63;
    const int wv = __builtin_amdgcn_readfirstlane(t >> 6);
    const int wb0 = blockIdx.x * 8, hb0 = blockIdx.y * 8;
    const int b  = blockIdx.z >> 2;
    const int gs = blockIdx.z & 3;
    const int ho = hb0 + (p >> 3), wo = wb0 + (p & 7);

    float acc[32];
#pragma unroll
    for (int o = 0; o < 32; ++o) acc[o] = 0.f;

    const int pairbase = gs * 36;
    const __half* hb = h3 + (size_t)b * 432 * HW + ho * WW + wo;
    const float*  xb = xt + (size_t)b * HW * 128;

    float py_n, px_n, m_n;                 // coords of the next chunk to gather

    // ---- prologue: coords(ch=0); gather ch=0 -> buf0; coords(ch=1) ----
    {
        int pair = pairbase + wv;
        int g = pair / 9, k = pair - (pair / 9) * 9;
        float dy = __half2float(hb[(size_t)(g * 18 + k * 2)     * HW]);
        float dx = __half2float(hb[(size_t)(g * 18 + k * 2 + 1) * HW]);
        m_n  = __half2float(hb[(size_t)(288 + g * 9 + k)        * HW]);
        py_n = dy + (float)(ho + k / 3 - 1);
        px_n = dx + (float)(wo + (k % 3) - 1);

        float fy = floorf(py_n), fx = floorf(px_n);
        int y0 = (int)fy, x0 = (int)fx;
        float wy = py_n - fy, wx = px_n - fx;
        int y0c = min(max(y0, 0), HH - 1),     y1c = min(max(y0 + 1, 0), HH - 1);
        int x0c = min(max(x0, 0), WW - 1),     x1c = min(max(x0 + 1, 0), WW - 1);
        float vy0 = ((unsigned)y0       < (unsigned)HH) ? 1.f : 0.f;
        float vy1 = ((unsigned)(y0 + 1) < (unsigned)HH) ? 1.f : 0.f;
        float vx0 = ((unsigned)x0       < (unsigned)WW) ? 1.f : 0.f;
        float vx1 = ((unsigned)(x0 + 1) < (unsigned)WW) ? 1.f : 0.f;
        float w00 = (1.f - wy) * (1.f - wx) * vy0 * vx0 * m_n;
        float w01 = (1.f - wy) * wx         * vy0 * vx1 * m_n;
        float w10 = wy         * (1.f - wx) * vy1 * vx0 * m_n;
        float w11 = wy         * wx         * vy1 * vx1 * m_n;
        const float* a00 = xb + (size_t)(y0c * WW + x0c) * 128 + g * 8;
        const float* a01 = xb + (size_t)(y0c * WW + x1c) * 128 + g * 8;
        const float* a10 = xb + (size_t)(y1c * WW + x0c) * 128 + g * 8;
        const float* a11 = xb + (size_t)(y1c * WW + x1c) * 128 + g * 8;
        f32x4 c00a = *(const f32x4*)a00, c00b = *(const f32x4*)(a00 + 4);
        f32x4 c01a = *(const f32x4*)a01, c01b = *(const f32x4*)(a01 + 4);
        f32x4 c10a = *(const f32x4*)a10, c10b = *(const f32x4*)(a10 + 4);
        f32x4 c11a = *(const f32x4*)a11, c11b = *(const f32x4*)(a11 + 4);
        float val[8];
        bilinear8(c00a, c00b, c01a, c01b, c10a, c10b, c11a, c11b, w00, w01, w10, w11, val);
#pragma unroll
        for (int c = 0; c < 8; ++c) s_val[0][wv][c][p] = val[c];
    }
    {
        int pair = pairbase + 4 + wv;
        int g = pair / 9, k = pair - (pair / 9) * 9;
        float dy = __half2float(hb[(size_t)(g * 18 + k * 2)     * HW]);
        float dx = __half2float(hb[(size_t)(g * 18 + k * 2 + 1) * HW]);
        m_n  = __half2float(hb[(size_t)(288 + g * 9 + k)        * HW]);
        py_n = dy + (float)(ho + k / 3 - 1);
        px_n = dx + (float)(wo + (k % 3) - 1);
    }
    __syncthreads();

    int cur = 0;
    for (int ch = 0; ch < 9; ++ch) {
        // A: h3 raw loads for chunk ch+2
        float rdy = 0.f, rdx = 0.f, rm = 0.f;
        if (ch < 7) {
            int pair = pairbase + (ch + 2) * 4 + wv;
            int g = pair / 9, k = pair - (pair / 9) * 9;
            rdy = __half2float(hb[(size_t)(g * 18 + k * 2)     * HW]);
            rdx = __half2float(hb[(size_t)(g * 18 + k * 2 + 1) * HW]);
            rm  = __half2float(hb[(size_t)(288 + g * 9 + k)    * HW]);
        }
        // B: issue corner loads for chunk ch+1
        f32x4 c00a, c00b, c01a, c01b, c10a, c10b, c11a, c11b;
        float w00 = 0.f, w01 = 0.f, w10 = 0.f, w11 = 0.f;
        if (ch < 8) {
            int pair = pairbase + (ch + 1) * 4 + wv;
            int g = pair / 9;
            float fy = floorf(py_n), fx = floorf(px_n);
            int y0 = (int)fy, x0 = (int)fx;
            float wy = py_n - fy, wx = px_n - fx;
            int y0c = min(max(y0, 0), HH - 1),     y1c = min(max(y0 + 1, 0), HH - 1);
            int x0c = min(max(x0, 0), WW - 1),     x1c = min(max(x0 + 1, 0), WW - 1);
            float vy0 = ((unsigned)y0       < (unsigned)HH) ? 1.f : 0.f;
            float vy1 = ((unsigned)(y0 + 1) < (unsigned)HH) ? 1.f : 0.f;
            float vx0 = ((unsigned)x0       < (unsigned)WW) ? 1.f : 0.f;
            float vx1 = ((unsigned)(x0 + 1) < (unsigned)WW) ? 1.f : 0.f;
            w00 = (1.f - wy) * (1.f - wx) * vy0 * vx0 * m_n;
            w01 = (1.f - wy) * wx         * vy0 * vx1 * m_n;
            w10 = wy         * (1.f - wx) * vy1 * vx0 * m_n;
            w11 = wy         * wx         * vy1 * vx1 * m_n;
            const float* a00 = xb + (size_t)(y0c * WW + x0c) * 128 + g * 8;
            const float* a01 = xb + (size_t)(y0c * WW + x1c) * 128 + g * 8;
            const float* a10 = xb + (size_t)(y1c * WW + x0c) * 128 + g * 8;
            const float* a11 = xb + (size_t)(y1c * WW + x1c) * 128 + g * 8;
            c00a = *(const f32x4*)a00; c00b = *(const f32x4*)(a00 + 4);
            c01a = *(const f32x4*)a01; c01b = *(const f32x4*)(a01 + 4);
            c10a = *(const f32x4*)a10; c10b = *(const f32x4*)(a10 + 4);
            c11a = *(const f32x4*)a11; c11b = *(const f32x4*)(a11 + 4);
        }
        // C: FMA chunk ch from s_val[cur]; weights via wave-uniform s_load
        const float* wtb = wT + (size_t)(pairbase + ch * 4) * 8 * 128 + wv * 32;
#pragma unroll
        for (int j = 0; j < 4; ++j) {
#pragma unroll
            for (int c = 0; c < 8; ++c) {
                float v = s_val[cur][j][c][p];
                const float* wp = wtb + (j * 8 + c) * 128;
#pragma unroll
                for (int o = 0; o < 32; ++o)
                    acc[o] = fmaf(v, wp[o], acc[o]);
            }
        }
        // D: bilinear + write s_val[cur^1]; coords for ch+2
        if (ch < 8) {
            float val[8];
            bilinear8(c00a, c00b, c01a, c01b, c10a, c10b, c11a, c11b, w00, w01, w10, w11, val);
#pragma unroll
            for (int c = 0; c < 8; ++c) s_val[cur ^ 1][wv][c][p] = val[c];
        }
        if (ch < 7) {
            int pair = pairbase + (ch + 2) * 4 + wv;
            int k = pair - (pair / 9) * 9;
            py_n = rdy + (float)(ho + k / 3 - 1);
            px_n = rdx + (float)(wo + (k % 3) - 1);
            m_n  = rm;
        }
        __syncthreads();
        cur ^= 1;
    }

    float* op = out + ((size_t)(b * 128) + wv * 32) * HW + ho * WW + wo;
#pragma unroll
    for (int o = 0; o < 32; ++o)
        atomicAdd(op + (size_t)o * HW, acc[o]);
}

extern "C" void kernel_launch(void* const* d_in, const int* in_sizes, int n_in,
                              void* d_out, int out_size, void* d_ws, size_t ws_size,
                              hipStream_t stream)
{
    const float* x    = (const float*)d_in[0];
    const float* ef   = (const float*)d_in[1];
    const float* f1   = (const float*)d_in[2];
    const float* f2   = (const float*)d_in[3];
    const float* wgt  = (const float*)d_in[4];
    const float* bias = (const float*)d_in[5];
    const float* cw0  = (const float*)d_in[6];
    const float* cb0  = (const float*)d_in[7];
    const float* cw1  = (const float*)d_in[8];
    const float* cb1  = (const float*)d_in[9];
    const float* cw2  = (const float*)d_in[10];
    const float* cb2  = (const float*)d_in[11];
    const float* cw3  = (const float*)d_in[12];
    const float* cb3  = (const float*)d_in[13];

    float* outp = (float*)d_out;
    char*  ws   = (char*)d_ws;

    // ---- ws layout (bytes) ----
    float*          wT   = (float*)         (ws + 0);           // 589,824
    unsigned short* W0h  = (unsigned short*)(ws + 589824);      // 958,464
    unsigned short* W0l  = (unsigned short*)(ws + 1548288);
    unsigned short* W1h  = (unsigned short*)(ws + 2506752);     // 294,912
    unsigned short* W1l  = (unsigned short*)(ws + 2801664);
    unsigned short* W2h  = (unsigned short*)(ws + 3096576);
    unsigned short* W2l  = (unsigned short*)(ws + 3391488);
    unsigned short* W3h  = (unsigned short*)(ws + 3686400);     // 1,179,648
    unsigned short* W3l  = (unsigned short*)(ws + 4866048);
    unsigned short* o0H  = (unsigned short*)(ws + 6045696);     // 7,864,320 each
    unsigned short* o0L  = (unsigned short*)(ws + 13910016);
    unsigned short* o1H  = (unsigned short*)(ws + 21774336);
    unsigned short* o1L  = (unsigned short*)(ws + 29638656);
    unsigned short* o2H  = (unsigned short*)(ws + 37502976);
    unsigned short* o2L  = (unsigned short*)(ws + 45367296);
    // h3 (fp16, 26,542,080 B) overlays dead o0/o1 region
    __half*         h3   = (__half*)        (ws + 6045696);
    // x transposed to NHWC fp32 (15,728,640 B); end = 68,960,256
    float*          xtp  = (float*)         (ws + 53231616);

    dim3 blk(256);

    // prep
    hipLaunchKernelGGL(xt_k,     dim3(HW / 64, BB), blk, 0, stream, x, xtp);
    hipLaunchKernelGGL(wtrans_k, dim3((128 * 128 * 9 + 255) / 256), blk, 0, stream, wgt, wT);
    hipLaunchKernelGGL(wsplit_k, dim3((9 * 128 * 416 + 255) / 256), blk, 0, stream, cw0, 128, 388, 128, 416, W0h, W0l);
    hipLaunchKernelGGL(wsplit_k, dim3((9 * 128 * 128 + 255) / 256), blk, 0, stream, cw1, 128, 128, 128, 128, W1h, W1l);
    hipLaunchKernelGGL(wsplit_k, dim3((9 * 128 * 128 + 255) / 256), blk, 0, stream, cw2, 128, 128, 128, 128, W2h, W2l);
    hipLaunchKernelGGL(wsplit_k, dim3((9 * 512 * 128 + 255) / 256), blk, 0, stream, cw3, 432, 128, 512, 128, W3h, W3l);

    dim3 gc (5, 24, BB);         // conv0/1/2: 4 rows x 32 cols tiles
    dim3 gc3(5, 24, BB * 4);     // conv3 (OCP=512 -> 4 m-blocks)

    hipLaunchKernelGGL((conv_mfma<1, 1, 13, 416, 128>), gc, blk, 0, stream,
                       ef, f1, f2, nullptr, nullptr, W0h, W0l, cb0, o0H, o0L, nullptr);
    hipLaunchKernelGGL((conv_mfma<0, 1, 4, 128, 128>), gc, blk, 0, stream,
                       nullptr, nullptr, nullptr, o0H, o0L, W1h, W1l, cb1, o1H, o1L, nullptr);
    hipLaunchKernelGGL((conv_mfma<0, 1, 4, 128, 128>), gc, blk, 0, stream,
                       nullptr, nullptr, nullptr, o1H, o1L, W2h, W2l, cb2, o2H, o2L, nullptr);
    hipLaunchKernelGGL((conv_mfma<0, 2, 4, 128, 512>), gc3, blk, 0, stream,
                       nullptr, f1, f2, o2H, o2L, W3h, W3l, cb3, nullptr, nullptr, h3);

    hipLaunchKernelGGL(init_out_k, dim3((BB * 128 * HW + 255) / 256), blk, 0, stream, bias, outp);
    hipLaunchKernelGGL(deform3_k, dim3(WW / 8, HH / 8, BB * 4), blk, 0, stream, xtp, h3, wT, outp);
}